// Round 16
// baseline (177.677 us; speedup 1.0000x reference)
//
#include <hip/hip_runtime.h>
#include <hip/hip_bf16.h>

// GraphConv x2 via dst-sorted CSR gather.
// CSR build with ZERO global returning atomics (LDS-atomic 4-phase, R14).
// Compute: gather1 (bf16), node_fused v4 (bf16 LDS act tiles, 16.9KB;
// R15 post-mortem: v3's 33KB fp32 tiles capped occupancy at 27% -> 49us),
// gather2 (bf16 hr). Direct register->global epilogue, 3 barriers.

#define NF 64
#define CSHIFT 7
#define CMASK 127
#define CMAX 1024   // supports N <= 131072

__device__ __forceinline__ unsigned short f2bf(float f) {
    __hip_bfloat16 h = __float2bfloat16(f);
    return *reinterpret_cast<unsigned short*>(&h);
}
__device__ __forceinline__ float bf2f(unsigned short u) {
    return __uint_as_float((unsigned int)u << 16);
}

// ---- prep: block0 = dtype detect; block1 = weight transpose; rest = x->bf16
__global__ __launch_bounds__(256) void prep(
    const unsigned* __restrict__ raw, int* __restrict__ flag, int E,
    const float* __restrict__ Wrel1, const float* __restrict__ Wroot1,
    const float* __restrict__ Wrel2, const float* __restrict__ Wroot2,
    float* __restrict__ W1relT, float* __restrict__ W1rootT, float* __restrict__ W2T,
    const float* __restrict__ x, unsigned short* __restrict__ xb, long long n4)
{
    if (blockIdx.x == 0) {
        __shared__ unsigned red[256];
        unsigned v = 0;
        int lim = (E < 4096) ? E : 4096;
        for (int i = threadIdx.x; i < lim; i += 256) v |= raw[2 * i + 1];
        red[threadIdx.x] = v;
        __syncthreads();
        for (int s = 128; s > 0; s >>= 1) {
            if (threadIdx.x < s) red[threadIdx.x] |= red[threadIdx.x + s];
            __syncthreads();
        }
        if (threadIdx.x == 0) *flag = (red[0] == 0) ? 1 : 0;
    } else if (blockIdx.x == 1) {
        int t = threadIdx.x;
        for (int i = t; i < 4096; i += 256) {
            int f = i >> 6, k = i & 63;
            W1relT[k * 64 + f]  = Wrel1[f * 64 + k];
            W1rootT[k * 64 + f] = Wroot1[f * 64 + k];
            W2T[k * 64 + f] = (f < 32) ? Wrel2[f * 64 + k] : Wroot2[(f - 32) * 64 + k];
        }
    } else {
        long long i = (long long)(blockIdx.x - 2) * 256 + threadIdx.x;
        long long stride = (long long)(gridDim.x - 2) * 256;
        for (; i < n4; i += stride) {
            float4 v = *(const float4*)(x + i * 4);
            ushort4 o;
            o.x = f2bf(v.x); o.y = f2bf(v.y); o.z = f2bf(v.z); o.w = f2bf(v.w);
            *(ushort4*)(xb + i * 4) = o;
        }
    }
}

// ---- p1: per-block coarse histogram into hb[c*B1 + blk] --------------------
__global__ __launch_bounds__(1024) void p1_hist(const void* __restrict__ raw,
                                                const int* __restrict__ flag,
                                                int* __restrict__ hb,
                                                int E, int C, int B1) {
    __shared__ int cnt[CMAX];
    int t = threadIdx.x;
    for (int i = t; i < C; i += 1024) cnt[i] = 0;
    __syncthreads();
    int fl = *flag;
    int ebase = blockIdx.x * 4096;
#pragma unroll
    for (int j = 0; j < 4; ++j) {
        int e = ebase + j * 1024 + t;
        if (e < E) {
            int d = fl ? (int)((const long long*)raw)[E + e] : ((const int*)raw)[E + e];
            atomicAdd(&cnt[d >> CSHIFT], 1);
        }
    }
    __syncthreads();
    for (int i = t; i < C; i += 1024) hb[i * B1 + blockIdx.x] = cnt[i];
}

// ---- flat exclusive scan over M elements (3 kernels, 1024-wide) -------------
__global__ __launch_bounds__(1024) void scan_k1(const int* __restrict__ in,
                                                int* __restrict__ out,
                                                int* __restrict__ bsums, int M) {
    __shared__ int tmp[1024];
    int tid = threadIdx.x;
    int i = blockIdx.x * 1024 + tid;
    int v = (i < M) ? in[i] : 0;
    tmp[tid] = v;
    __syncthreads();
    for (int off = 1; off < 1024; off <<= 1) {
        int t = (tid >= off) ? tmp[tid - off] : 0;
        __syncthreads();
        tmp[tid] += t;
        __syncthreads();
    }
    if (i < M) out[i] = tmp[tid] - v;
    if (tid == 1023) bsums[blockIdx.x] = tmp[tid];
}

__global__ __launch_bounds__(1024) void scan_k2(int* __restrict__ bsums, int nb) {
    __shared__ int tmp[1024];
    int tid = threadIdx.x;
    int v = (tid < nb) ? bsums[tid] : 0;
    tmp[tid] = v;
    __syncthreads();
    for (int off = 1; off < 1024; off <<= 1) {
        int t = (tid >= off) ? tmp[tid - off] : 0;
        __syncthreads();
        tmp[tid] += t;
        __syncthreads();
    }
    if (tid < nb) bsums[tid] = tmp[tid] - v;
}

__global__ __launch_bounds__(1024) void scan_k3(int* __restrict__ out,
                                                const int* __restrict__ bsums, int M) {
    int i = blockIdx.x * 1024 + threadIdx.x;
    if (i >= M) return;
    out[i] += bsums[blockIdx.x];
}

// ---- p3: scatter edges to bucket-partitioned part[] (LDS returning atomics) -
__global__ __launch_bounds__(1024) void p3_scatter(const void* __restrict__ raw,
                                                   const int* __restrict__ flag,
                                                   const float* __restrict__ ea,
                                                   const int* __restrict__ off,
                                                   long long* __restrict__ part,
                                                   int E, int C, int B1) {
    __shared__ int lcur[CMAX];
    int t = threadIdx.x;
    for (int i = t; i < C; i += 1024) lcur[i] = off[i * B1 + blockIdx.x];
    __syncthreads();
    int fl = *flag;
    int ebase = blockIdx.x * 4096;
#pragma unroll
    for (int j = 0; j < 4; ++j) {
        int e = ebase + j * 1024 + t;
        if (e < E) {
            int s, d;
            if (fl) { const long long* p = (const long long*)raw; s = (int)p[e]; d = (int)p[E + e]; }
            else    { const int* p = (const int*)raw; s = p[e]; d = p[E + e]; }
            float w = ea[e];
            int slot = atomicAdd(&lcur[d >> CSHIFT], 1);
            long long pk = (unsigned int)(s | ((d & CMASK) << 20))
                         | ((long long)__float_as_int(w) << 32);
            part[slot] = pk;
        }
    }
}

// ---- p4: per-bucket exact grouping; writes deg, base, csr -------------------
__global__ __launch_bounds__(256) void p4_build(const int* __restrict__ off,
                                                const long long* __restrict__ part,
                                                int2* __restrict__ csr,
                                                int* __restrict__ deg,
                                                int* __restrict__ base,
                                                int E, int N, int C, int B1) {
    __shared__ int ldeg[128], tmp[128], lcur[128];
    int c = blockIdx.x, t = threadIdx.x;
    int bstart = off[c * B1];
    int bend = (c + 1 < C) ? off[(c + 1) * B1] : E;
    if (t < 128) ldeg[t] = 0;
    __syncthreads();
    for (int i = bstart + t; i < bend; i += 256) {
        int lo = (int)part[i];
        atomicAdd(&ldeg[(lo >> 20) & CMASK], 1);
    }
    __syncthreads();
    if (t < 128) tmp[t] = ldeg[t];
    __syncthreads();
    for (int o = 1; o < 128; o <<= 1) {
        int v = (t < 128 && t >= o) ? tmp[t - o] : 0;
        __syncthreads();
        if (t < 128) tmp[t] += v;
        __syncthreads();
    }
    if (t < 128) {
        int ex = tmp[t] - ldeg[t];
        lcur[t] = ex;
        int n = (c << CSHIFT) + t;
        if (n < N) { deg[n] = ldeg[t]; base[n] = bstart + ex; }
    }
    __syncthreads();
    for (int i = bstart + t; i < bend; i += 256) {
        long long pk = part[i];
        int lo = (int)pk;
        int r = atomicAdd(&lcur[(lo >> 20) & CMASK], 1);
        csr[bstart + r] = make_int2(lo & 0xFFFFF, (int)(pk >> 32));
    }
}

// ---- gather1: aggb[n] = bf16((sum_e w*xb[src])/max(deg,1)) ------------------
__global__ __launch_bounds__(256) void gather1(
    const unsigned short* __restrict__ xb, const int2* __restrict__ csr,
    const int* __restrict__ base, const int* __restrict__ deg,
    unsigned short* __restrict__ aggb, int N)
{
    int lane = threadIdx.x & 63;
    int wid = blockIdx.x * 4 + (threadIdx.x >> 6);
    int stride = gridDim.x * 4;
    for (int n = wid; n < N; n += stride) {
        int b = __builtin_amdgcn_readfirstlane(base[n]);
        int dg = __builtin_amdgcn_readfirstlane(deg[n]);
        float acc0 = 0.f, acc1 = 0.f, acc2 = 0.f, acc3 = 0.f;
        int i = b, e = b + dg;
        for (; i + 8 <= e; i += 8) {
            int2 r0 = csr[i], r1 = csr[i + 1], r2 = csr[i + 2], r3 = csr[i + 3];
            int2 r4 = csr[i + 4], r5 = csr[i + 5], r6 = csr[i + 6], r7 = csr[i + 7];
            float v0 = bf2f(xb[(size_t)r0.x * 64 + lane]);
            float v1 = bf2f(xb[(size_t)r1.x * 64 + lane]);
            float v2 = bf2f(xb[(size_t)r2.x * 64 + lane]);
            float v3 = bf2f(xb[(size_t)r3.x * 64 + lane]);
            float v4 = bf2f(xb[(size_t)r4.x * 64 + lane]);
            float v5 = bf2f(xb[(size_t)r5.x * 64 + lane]);
            float v6 = bf2f(xb[(size_t)r6.x * 64 + lane]);
            float v7 = bf2f(xb[(size_t)r7.x * 64 + lane]);
            acc0 = fmaf(__int_as_float(r0.y), v0, acc0);
            acc1 = fmaf(__int_as_float(r1.y), v1, acc1);
            acc2 = fmaf(__int_as_float(r2.y), v2, acc2);
            acc3 = fmaf(__int_as_float(r3.y), v3, acc3);
            acc0 = fmaf(__int_as_float(r4.y), v4, acc0);
            acc1 = fmaf(__int_as_float(r5.y), v5, acc1);
            acc2 = fmaf(__int_as_float(r6.y), v6, acc2);
            acc3 = fmaf(__int_as_float(r7.y), v7, acc3);
        }
        for (; i + 4 <= e; i += 4) {
            int2 r0 = csr[i], r1 = csr[i + 1], r2 = csr[i + 2], r3 = csr[i + 3];
            acc0 = fmaf(__int_as_float(r0.y), bf2f(xb[(size_t)r0.x * 64 + lane]), acc0);
            acc1 = fmaf(__int_as_float(r1.y), bf2f(xb[(size_t)r1.x * 64 + lane]), acc1);
            acc2 = fmaf(__int_as_float(r2.y), bf2f(xb[(size_t)r2.x * 64 + lane]), acc2);
            acc3 = fmaf(__int_as_float(r3.y), bf2f(xb[(size_t)r3.x * 64 + lane]), acc3);
        }
        for (; i < e; ++i) {
            int2 r = csr[i];
            acc0 = fmaf(__int_as_float(r.y), bf2f(xb[(size_t)r.x * 64 + lane]), acc0);
        }
        float inv = 1.0f / fmaxf((float)dg, 1.0f);
        aggb[(size_t)n * 64 + lane] = f2bf(((acc0 + acc1) + (acc2 + acc3)) * inv);
    }
}

// ---- node_fused v4: bf16 LDS act tiles [64][66] ushort ----------------------
// Column b32 read delivers 2 k-values; bank = (lane*33 + k/2)%32 -> 2-way free.
// lane=node, 4 waves own 16 features each; weights via wave-uniform s_loads.
// Epilogue writes registers straight to global (no LDS round trip).
__global__ __launch_bounds__(256) void node_fused(
    const unsigned short* __restrict__ aggb, const unsigned short* __restrict__ xb,
    const float* __restrict__ W1relT, const float* __restrict__ brel1,
    const float* __restrict__ W1rootT, const float* __restrict__ W2T,
    const float* __restrict__ brel2,
    unsigned short* __restrict__ hrb, float* __restrict__ hro, int N)
{
    __shared__ unsigned short Ag[64 * 66];
    __shared__ unsigned short Xt[64 * 66];
    int t = threadIdx.x;
    int lane = t & 63;
    int fbase = __builtin_amdgcn_readfirstlane((t >> 6) * 16);
    int n0 = blockIdx.x * 64;
    int rem = N - n0; if (rem > 64) rem = 64;

    // stage both tiles: pure bf16 copy, 2 k-values per uint
    for (int idx = t; idx < 1024; idx += 256) {
        int m = idx >> 4, c = idx & 15;
        int srcn = n0 + ((m < rem) ? m : 0);
        unsigned ua = *(const unsigned*)(aggb + (size_t)srcn * 64 + c * 4);
        unsigned ub = *(const unsigned*)(aggb + (size_t)srcn * 64 + c * 4 + 2);
        unsigned va = *(const unsigned*)(xb + (size_t)srcn * 64 + c * 4);
        unsigned vb = *(const unsigned*)(xb + (size_t)srcn * 64 + c * 4 + 2);
        *(unsigned*)(&Ag[m * 66 + c * 4]) = ua;
        *(unsigned*)(&Ag[m * 66 + c * 4 + 2]) = ub;
        *(unsigned*)(&Xt[m * 66 + c * 4]) = va;
        *(unsigned*)(&Xt[m * 66 + c * 4 + 2]) = vb;
    }

    float4 acc0 = *(const float4*)(brel1 + fbase);
    float4 acc1 = *(const float4*)(brel1 + fbase + 4);
    float4 acc2 = *(const float4*)(brel1 + fbase + 8);
    float4 acc3 = *(const float4*)(brel1 + fbase + 12);
    __syncthreads();                               // (1)

#define K_STEP12(K, AV, BV)                                                 \
    {                                                                       \
        const float* wr = W1relT + (K) * 64 + fbase;                        \
        const float* wo = W1rootT + (K) * 64 + fbase;                       \
        float4 r0 = *(const float4*)(wr),     r1 = *(const float4*)(wr + 4);\
        float4 r2 = *(const float4*)(wr + 8), r3 = *(const float4*)(wr + 12);\
        float4 o0 = *(const float4*)(wo),     o1 = *(const float4*)(wo + 4);\
        float4 o2 = *(const float4*)(wo + 8), o3 = *(const float4*)(wo + 12);\
        acc0.x = fmaf(AV, r0.x, acc0.x); acc0.y = fmaf(AV, r0.y, acc0.y);   \
        acc0.z = fmaf(AV, r0.z, acc0.z); acc0.w = fmaf(AV, r0.w, acc0.w);   \
        acc1.x = fmaf(AV, r1.x, acc1.x); acc1.y = fmaf(AV, r1.y, acc1.y);   \
        acc1.z = fmaf(AV, r1.z, acc1.z); acc1.w = fmaf(AV, r1.w, acc1.w);   \
        acc2.x = fmaf(AV, r2.x, acc2.x); acc2.y = fmaf(AV, r2.y, acc2.y);   \
        acc2.z = fmaf(AV, r2.z, acc2.z); acc2.w = fmaf(AV, r2.w, acc2.w);   \
        acc3.x = fmaf(AV, r3.x, acc3.x); acc3.y = fmaf(AV, r3.y, acc3.y);   \
        acc3.z = fmaf(AV, r3.z, acc3.z); acc3.w = fmaf(AV, r3.w, acc3.w);   \
        acc0.x = fmaf(BV, o0.x, acc0.x); acc0.y = fmaf(BV, o0.y, acc0.y);   \
        acc0.z = fmaf(BV, o0.z, acc0.z); acc0.w = fmaf(BV, o0.w, acc0.w);   \
        acc1.x = fmaf(BV, o1.x, acc1.x); acc1.y = fmaf(BV, o1.y, acc1.y);   \
        acc1.z = fmaf(BV, o1.z, acc1.z); acc1.w = fmaf(BV, o1.w, acc1.w);   \
        acc2.x = fmaf(BV, o2.x, acc2.x); acc2.y = fmaf(BV, o2.y, acc2.y);   \
        acc2.z = fmaf(BV, o2.z, acc2.z); acc2.w = fmaf(BV, o2.w, acc2.w);   \
        acc3.x = fmaf(BV, o3.x, acc3.x); acc3.y = fmaf(BV, o3.y, acc3.y);   \
        acc3.z = fmaf(BV, o3.z, acc3.z); acc3.w = fmaf(BV, o3.w, acc3.w);   \
    }

    for (int k4 = 0; k4 < 16; ++k4) {
        int kb = k4 * 4;
        unsigned ua0 = *(const unsigned*)(&Ag[lane * 66 + kb]);
        unsigned ua1 = *(const unsigned*)(&Ag[lane * 66 + kb + 2]);
        unsigned ub0 = *(const unsigned*)(&Xt[lane * 66 + kb]);
        unsigned ub1 = *(const unsigned*)(&Xt[lane * 66 + kb + 2]);
        float a0 = __uint_as_float(ua0 << 16), a1 = __uint_as_float(ua0 & 0xffff0000u);
        float a2 = __uint_as_float(ua1 << 16), a3 = __uint_as_float(ua1 & 0xffff0000u);
        float b0 = __uint_as_float(ub0 << 16), b1 = __uint_as_float(ub0 & 0xffff0000u);
        float b2 = __uint_as_float(ub1 << 16), b3 = __uint_as_float(ub1 & 0xffff0000u);
        K_STEP12(kb + 0, a0, b0)
        K_STEP12(kb + 1, a1, b1)
        K_STEP12(kb + 2, a2, b2)
        K_STEP12(kb + 3, a3, b3)
    }
#undef K_STEP12

    acc0.x = 1.f / (1.f + __expf(-acc0.x)); acc0.y = 1.f / (1.f + __expf(-acc0.y));
    acc0.z = 1.f / (1.f + __expf(-acc0.z)); acc0.w = 1.f / (1.f + __expf(-acc0.w));
    acc1.x = 1.f / (1.f + __expf(-acc1.x)); acc1.y = 1.f / (1.f + __expf(-acc1.y));
    acc1.z = 1.f / (1.f + __expf(-acc1.z)); acc1.w = 1.f / (1.f + __expf(-acc1.w));
    acc2.x = 1.f / (1.f + __expf(-acc2.x)); acc2.y = 1.f / (1.f + __expf(-acc2.y));
    acc2.z = 1.f / (1.f + __expf(-acc2.z)); acc2.w = 1.f / (1.f + __expf(-acc2.w));
    acc3.x = 1.f / (1.f + __expf(-acc3.x)); acc3.y = 1.f / (1.f + __expf(-acc3.y));
    acc3.z = 1.f / (1.f + __expf(-acc3.z)); acc3.w = 1.f / (1.f + __expf(-acc3.w));
    __syncthreads();                               // (2) phase-1/2 reads done

    // h -> Ag tile as packed bf16 (8 b32 stores)
    {
        unsigned short* hrow = &Ag[lane * 66 + fbase];
        *(unsigned*)(hrow + 0)  = (unsigned)f2bf(acc0.x) | ((unsigned)f2bf(acc0.y) << 16);
        *(unsigned*)(hrow + 2)  = (unsigned)f2bf(acc0.z) | ((unsigned)f2bf(acc0.w) << 16);
        *(unsigned*)(hrow + 4)  = (unsigned)f2bf(acc1.x) | ((unsigned)f2bf(acc1.y) << 16);
        *(unsigned*)(hrow + 6)  = (unsigned)f2bf(acc1.z) | ((unsigned)f2bf(acc1.w) << 16);
        *(unsigned*)(hrow + 8)  = (unsigned)f2bf(acc2.x) | ((unsigned)f2bf(acc2.y) << 16);
        *(unsigned*)(hrow + 10) = (unsigned)f2bf(acc2.z) | ((unsigned)f2bf(acc2.w) << 16);
        *(unsigned*)(hrow + 12) = (unsigned)f2bf(acc3.x) | ((unsigned)f2bf(acc3.y) << 16);
        *(unsigned*)(hrow + 14) = (unsigned)f2bf(acc3.z) | ((unsigned)f2bf(acc3.w) << 16);
    }
    __syncthreads();                               // (3)

    // phase 3: out2[j-slice] = h @ W2T (+b2 for j>=32)
    if (fbase < 32) {
        acc0 = make_float4(0.f, 0.f, 0.f, 0.f);
        acc1 = acc0; acc2 = acc0; acc3 = acc0;
    } else {
        acc0 = *(const float4*)(brel2 + fbase - 32);
        acc1 = *(const float4*)(brel2 + fbase - 28);
        acc2 = *(const float4*)(brel2 + fbase - 24);
        acc3 = *(const float4*)(brel2 + fbase - 20);
    }

#define K_STEP3(K, AV)                                                      \
    {                                                                       \
        const float* wk = W2T + (K) * 64 + fbase;                           \
        float4 w0 = *(const float4*)(wk),     w1 = *(const float4*)(wk + 4);\
        float4 w2 = *(const float4*)(wk + 8), w3 = *(const float4*)(wk + 12);\
        acc0.x = fmaf(AV, w0.x, acc0.x); acc0.y = fmaf(AV, w0.y, acc0.y);   \
        acc0.z = fmaf(AV, w0.z, acc0.z); acc0.w = fmaf(AV, w0.w, acc0.w);   \
        acc1.x = fmaf(AV, w1.x, acc1.x); acc1.y = fmaf(AV, w1.y, acc1.y);   \
        acc1.z = fmaf(AV, w1.z, acc1.z); acc1.w = fmaf(AV, w1.w, acc1.w);   \
        acc2.x = fmaf(AV, w2.x, acc2.x); acc2.y = fmaf(AV, w2.y, acc2.y);   \
        acc2.z = fmaf(AV, w2.z, acc2.z); acc2.w = fmaf(AV, w2.w, acc2.w);   \
        acc3.x = fmaf(AV, w3.x, acc3.x); acc3.y = fmaf(AV, w3.y, acc3.y);   \
        acc3.z = fmaf(AV, w3.z, acc3.z); acc3.w = fmaf(AV, w3.w, acc3.w);   \
    }

    for (int k4 = 0; k4 < 16; ++k4) {
        int kb = k4 * 4;
        unsigned ua0 = *(const unsigned*)(&Ag[lane * 66 + kb]);
        unsigned ua1 = *(const unsigned*)(&Ag[lane * 66 + kb + 2]);
        float a0 = __uint_as_float(ua0 << 16), a1 = __uint_as_float(ua0 & 0xffff0000u);
        float a2 = __uint_as_float(ua1 << 16), a3 = __uint_as_float(ua1 & 0xffff0000u);
        K_STEP3(kb + 0, a0)
        K_STEP3(kb + 1, a1)
        K_STEP3(kb + 2, a2)
        K_STEP3(kb + 3, a3)
    }
#undef K_STEP3

    // epilogue: registers -> global directly (node = lane)
    if (lane < rem) {
        int n = n0 + lane;
        if (fbase < 32) {
            uint4 v0, v1;
            v0.x = (unsigned)f2bf(acc0.x) | ((unsigned)f2bf(acc0.y) << 16);
            v0.y = (unsigned)f2bf(acc0.z) | ((unsigned)f2bf(acc0.w) << 16);
            v0.z = (unsigned)f2bf(acc1.x) | ((unsigned)f2bf(acc1.y) << 16);
            v0.w = (unsigned)f2bf(acc1.z) | ((unsigned)f2bf(acc1.w) << 16);
            v1.x = (unsigned)f2bf(acc2.x) | ((unsigned)f2bf(acc2.y) << 16);
            v1.y = (unsigned)f2bf(acc2.z) | ((unsigned)f2bf(acc2.w) << 16);
            v1.z = (unsigned)f2bf(acc3.x) | ((unsigned)f2bf(acc3.y) << 16);
            v1.w = (unsigned)f2bf(acc3.z) | ((unsigned)f2bf(acc3.w) << 16);
            *(uint4*)(hrb + (size_t)n * 32 + fbase) = v0;
            *(uint4*)(hrb + (size_t)n * 32 + fbase + 8) = v1;
        } else {
            float* dst = hro + (size_t)n * 32 + (fbase - 32);
            *(float4*)(dst + 0) = acc0;
            *(float4*)(dst + 4) = acc1;
            *(float4*)(dst + 8) = acc2;
            *(float4*)(dst + 12) = acc3;
        }
    }
}

// ---- gather2 + epilogue: out = agg2/deg + hro -------------------------------
__global__ __launch_bounds__(256) void gather2(
    const unsigned short* __restrict__ hrb, const float* __restrict__ hro,
    const int2* __restrict__ csr, const int* __restrict__ base,
    const int* __restrict__ deg, float* __restrict__ out, int N)
{
    int lane = threadIdx.x & 63;
    int j = lane & 31, half = lane >> 5;
    int wid = blockIdx.x * 4 + (threadIdx.x >> 6);
    int stride = gridDim.x * 4;
    for (int n = wid; n < N; n += stride) {
        int b = __builtin_amdgcn_readfirstlane(base[n]);
        int dg = __builtin_amdgcn_readfirstlane(deg[n]);
        float a0 = 0.f, a1 = 0.f, a2 = 0.f, a3 = 0.f;
        int i = b + half, e = b + dg;
        for (; i + 8 <= e + half; i += 8) {
            int2 r0 = csr[i], r1 = csr[i + 2], r2 = csr[i + 4], r3 = csr[i + 6];
            a0 = fmaf(__int_as_float(r0.y), bf2f(hrb[(size_t)r0.x * 32 + j]), a0);
            a1 = fmaf(__int_as_float(r1.y), bf2f(hrb[(size_t)r1.x * 32 + j]), a1);
            a2 = fmaf(__int_as_float(r2.y), bf2f(hrb[(size_t)r2.x * 32 + j]), a2);
            a3 = fmaf(__int_as_float(r3.y), bf2f(hrb[(size_t)r3.x * 32 + j]), a3);
        }
        for (; i < e; i += 2) {
            int2 r = csr[i];
            a0 = fmaf(__int_as_float(r.y), bf2f(hrb[(size_t)r.x * 32 + j]), a0);
        }
        float acc = (a0 + a1) + (a2 + a3);
        acc += __shfl_xor(acc, 32);
        if (half == 0) {
            float inv = 1.0f / fmaxf((float)dg, 1.0f);
            out[(size_t)n * 32 + j] = acc * inv + hro[(size_t)n * 32 + j];
        }
    }
}

extern "C" void kernel_launch(void* const* d_in, const int* in_sizes, int n_in,
                              void* d_out, int out_size, void* d_ws, size_t ws_size,
                              hipStream_t stream) {
    const float* x      = (const float*)d_in[0];
    const void*  ei_raw = d_in[1];
    const float* ea     = (const float*)d_in[2];
    const float* Wrel1  = (const float*)d_in[3];
    const float* brel1  = (const float*)d_in[4];
    const float* Wroot1 = (const float*)d_in[5];
    const float* Wrel2  = (const float*)d_in[6];
    const float* brel2  = (const float*)d_in[7];
    const float* Wroot2 = (const float*)d_in[8];
    float* out = (float*)d_out;

    const int N = in_sizes[0] / NF;          // 100000
    const int E = in_sizes[2];               // 1000000
    const int C  = (N + CMASK) >> CSHIFT;    // 782 coarse buckets
    const int B1 = (E + 4095) / 4096;        // 245 edge blocks
    const int M  = C * B1;                   // 191590
    const int nbM = (M + 1023) / 1024;       // 188

    // workspace layout
    long long* part = (long long*)d_ws;                 // E (8 MB)
    int2*  csr     = (int2*)(part + E);                 // E (8 MB); hb overlaps pre-p4
    int*   off     = (int*)(csr + E);                   // M
    int*   bsums   = off + M;                           // nbM (+pad)
    int*   flag    = bsums + 1024;                      // 1 (+3 pad)
    int*   deg     = flag + 4;                          // N
    int*   base    = deg + N;                           // N
    float* hro     = (float*)(base + N);                // N*32 fp32
    float* W1relT  = hro + (size_t)N * 32;              // 4096
    float* W1rootT = W1relT + 4096;                     // 4096
    float* W2T     = W1rootT + 4096;                    // 4096
    unsigned short* xb   = (unsigned short*)(W2T + 4096);  // N*64 bf16
    unsigned short* aggb = xb + (size_t)N * 64;            // N*64 bf16
    unsigned short* hrb  = aggb + (size_t)N * 64;          // N*32 bf16

    prep<<<2048, 256, 0, stream>>>((const unsigned*)ei_raw, flag, E,
                                   Wrel1, Wroot1, Wrel2, Wroot2,
                                   W1relT, W1rootT, W2T, x, xb, (long long)N * 16);
    p1_hist<<<B1, 1024, 0, stream>>>(ei_raw, flag, (int*)csr, E, C, B1);
    scan_k1<<<nbM, 1024, 0, stream>>>((int*)csr, off, bsums, M);
    scan_k2<<<1, 1024, 0, stream>>>(bsums, nbM);
    scan_k3<<<nbM, 1024, 0, stream>>>(off, bsums, M);
    p3_scatter<<<B1, 1024, 0, stream>>>(ei_raw, flag, ea, off, part, E, C, B1);
    p4_build<<<C, 256, 0, stream>>>(off, part, csr, deg, base, E, N, C, B1);

    gather1<<<2048, 256, 0, stream>>>(xb, csr, base, deg, aggb, N);
    node_fused<<<(N + 63) / 64, 256, 0, stream>>>(aggb, xb, W1relT, brel1, W1rootT,
                                                  W2T, brel2, hrb, hro, N);
    gather2<<<2048, 256, 0, stream>>>(hrb, hro, csr, base, deg, out, N);
}